// Round 1
// baseline (921.266 us; speedup 1.0000x reference)
//
#include <hip/hip_runtime.h>
#include <math.h>

#define L1B 16384                  // 14-bit level-1 bins
#define L1W (L1B / 2)              // packed u16 words per block hist
#define H1_BLOCKS 512
#define SLOTS 32
#define L2BITS 18
#define L2B (1 << L2BITS)          // 262144 level-2 bins per slot
#define L2GROUPS (L2B / 256)       // 1024 coarse groups per slot

// ---------------- device-global scratch ----------------
__device__ unsigned int g_part1[H1_BLOCKS * L1W];      // 16 MB, fully overwritten
__device__ unsigned int g_hist1[L1B];                  // zeroed, atomic-accumulated
__device__ unsigned int g_coarse1[L1B / 256];          // 64 groups, zeroed
__device__ unsigned int g_hist2[SLOTS * L2B];          // 32 MB, zeroed; sparse atomics
__device__ unsigned int g_coarse2[SLOTS * L2GROUPS];   // written for used slots only
__device__ unsigned char g_sid1[L1B];                  // slot+1 per level-1 bin, zeroed
__device__ int          g_nslot;

__device__ unsigned int g_bin1[32], g_res1[32];
__device__ int          g_slot1[32];
__device__ float        g_mn[16], g_mx[16];
__device__ unsigned int g_tkey[16];

// monotone float->uint key
__device__ __forceinline__ unsigned int f2key(float f) {
    unsigned int b = __float_as_uint(f);
    return (b & 0x80000000u) ? ~b : (b | 0x80000000u);
}
__device__ __forceinline__ float key2f(unsigned int k) {
    unsigned int b = (k & 0x80000000u) ? (k & 0x7FFFFFFFu) : ~k;
    return __uint_as_float(b);
}

// ---------------- zero ----------------
__global__ void zero_scratch() {
    int i = blockIdx.x * blockDim.x + threadIdx.x;
    int stride = gridDim.x * blockDim.x;
    for (int j = i; j < SLOTS * L2B; j += stride) g_hist2[j] = 0u;
    for (int j = i; j < L1B; j += stride) g_hist1[j] = 0u;
    unsigned int* s1 = (unsigned int*)g_sid1;
    for (int j = i; j < L1B / 4; j += stride) s1[j] = 0u;
    if (i < L1B / 256) g_coarse1[i] = 0u;
}

// ---------------- level 1: 14-bit histogram (LDS packed u16) ----------------
__global__ void hist1_kernel(const float4* __restrict__ x, int n4) {
    __shared__ unsigned int h[L1W];  // 32 KB
    for (int j = threadIdx.x; j < L1W; j += blockDim.x) h[j] = 0u;
    __syncthreads();
    int stride = gridDim.x * blockDim.x;
    for (int i = blockIdx.x * blockDim.x + threadIdx.x; i < n4; i += stride) {
        float4 v = x[i];
        float vv[4] = {v.x, v.y, v.z, v.w};
#pragma unroll
        for (int k = 0; k < 4; ++k) {
            unsigned int b = f2key(vv[k]) >> L2BITS;
            atomicAdd(&h[b >> 1], 1u << ((b & 1) << 4));
        }
    }
    __syncthreads();
    for (int j = threadIdx.x; j < L1W; j += blockDim.x)
        g_part1[blockIdx.x * L1W + j] = h[j];
}

// 64K threads: word w summed over 8 chunks of 64 blocks, atomic-merged
__global__ void reduce1_kernel() {
    int t = blockIdx.x * blockDim.x + threadIdx.x;  // 65536 threads
    int w = t & (L1W - 1);
    int chunk = t >> 13;  // 0..7
    unsigned int lo = 0, hi = 0;
    for (int b = chunk * 64; b < chunk * 64 + 64; ++b) {
        unsigned int u = g_part1[b * L1W + w];
        lo += u & 0xFFFFu;
        hi += u >> 16;
    }
    atomicAdd(&g_hist1[2 * w], lo);
    atomicAdd(&g_hist1[2 * w + 1], hi);
    atomicAdd(&g_coarse1[w >> 7], lo + hi);
}

// ---------------- wave-parallel rank select (broadcast result to all lanes) ----
__device__ __forceinline__ void wave_select(const unsigned int* __restrict__ hist,
                                            int nbins, unsigned int r,
                                            unsigned int* out_bin, unsigned int* out_res) {
    int lane = threadIdx.x & 63;
    unsigned int base = 0;
    for (int k = 0; k < nbins; k += 64) {
        unsigned int v = hist[k + lane];
        unsigned int incl = v;
#pragma unroll
        for (int off = 1; off < 64; off <<= 1) {
            unsigned int t = (unsigned int)__shfl_up((int)incl, off, 64);
            if (lane >= off) incl += t;
        }
        unsigned int total = (unsigned int)__shfl((int)incl, 63, 64);
        if (r < base + total) {  // uniform branch
            unsigned long long m = __ballot(base + incl > r);
            int fl = __ffsll((long long)m) - 1;
            unsigned int incl_fl = (unsigned int)__shfl((int)incl, fl, 64);
            unsigned int v_fl = (unsigned int)__shfl((int)v, fl, 64);
            *out_bin = (unsigned int)(k + fl);
            *out_res = r - (base + incl_fl - v_fl);
            return;
        }
        base += total;
    }
    *out_bin = (unsigned int)(nbins - 1);
    *out_res = 0;  // unreachable
}

// ---------------- select level-1 boundaries + slot assignment (fused) ----------
__global__ void select1_kernel(unsigned int n) {
    __shared__ unsigned int s_bin[32], s_res[32];
    int wid = threadIdx.x >> 6;  // 16 waves
    unsigned int M = n >> 4;
    for (int i = wid; i < 32; i += 16) {
        unsigned int c = (unsigned int)(i >> 1);
        unsigned int r = (i & 1) ? ((c + 1) * M - 1u) : (c * M);
        unsigned int g, rg, b, res;
        wave_select(g_coarse1, L1B / 256, r, &g, &rg);
        wave_select(g_hist1 + (g << 8), 256, rg, &b, &res);
        if ((threadIdx.x & 63) == 0) { s_bin[i] = (g << 8) | b; s_res[i] = res; }
    }
    __syncthreads();
    if (threadIdx.x == 0) {
        unsigned int uniq[32];
        int nu = 0;
        for (int i = 0; i < 32; ++i) {
            unsigned int b = s_bin[i];
            int s = -1;
            for (int j = 0; j < nu; ++j) if (uniq[j] == b) { s = j; break; }
            if (s < 0) { s = nu; uniq[nu++] = b; g_sid1[b] = (unsigned char)(s + 1); }
            g_slot1[i] = s;
            g_bin1[i] = b;
            g_res1[i] = s_res[i];
        }
        g_nslot = nu;
    }
}

// ---------------- level 2: sparse 18-bit refinement (global atomics) ----------
__global__ void hist2_kernel(const float4* __restrict__ x, int n4) {
    __shared__ unsigned char sid1[L1B];  // 16 KB
    unsigned int* s1w = (unsigned int*)sid1;
    for (int j = threadIdx.x; j < L1B / 4; j += blockDim.x) s1w[j] = ((const unsigned int*)g_sid1)[j];
    __syncthreads();
    int stride = gridDim.x * blockDim.x;
    for (int i = blockIdx.x * blockDim.x + threadIdx.x; i < n4; i += stride) {
        float4 v = x[i];
        float vv[4] = {v.x, v.y, v.z, v.w};
#pragma unroll
        for (int k = 0; k < 4; ++k) {
            unsigned int key = f2key(vv[k]);
            unsigned int s = sid1[key >> L2BITS];
            if (s) atomicAdd(&g_hist2[((s - 1) << L2BITS) | (key & (L2B - 1))], 1u);
        }
    }
}

// coarse sums over 256-bin groups, one wave per group, used slots only
__global__ void coarse2_kernel() {
    int gw = (blockIdx.x * blockDim.x + threadIdx.x) >> 6;  // global wave = group id
    int slot = gw >> 10;
    if (slot >= g_nslot) return;
    int lane = threadIdx.x & 63;
    const uint4* p = (const uint4*)&g_hist2[gw << 8];
    uint4 v = p[lane];
    unsigned int s = v.x + v.y + v.z + v.w;
#pragma unroll
    for (int off = 32; off; off >>= 1) s += (unsigned int)__shfl_down((int)s, off, 64);
    if (lane == 0) g_coarse2[gw] = s;
}

// ---------------- select level-2 + finalize (fused) ----------------
__global__ void select2_kernel() {
    __shared__ unsigned int s_key[32];
    int wid = threadIdx.x >> 6;  // 16 waves
    for (int i = wid; i < 32; i += 16) {
        int s = g_slot1[i];
        unsigned int r = g_res1[i];
        unsigned int g, rg, b, res;
        wave_select(g_coarse2 + (s << 10), L2GROUPS, r, &g, &rg);
        wave_select(g_hist2 + (s << L2BITS) + (g << 8), 256, rg, &b, &res);
        if ((threadIdx.x & 63) == 0)
            s_key[i] = (g_bin1[i] << L2BITS) | (g << 8) | b;  // exact 32-bit key
    }
    __syncthreads();
    if (threadIdx.x < 16) {
        int c = threadIdx.x;
        unsigned int klo = s_key[2 * c];
        unsigned int khi = s_key[2 * c + 1];
        g_mn[c] = key2f(klo);
        g_mx[c] = key2f(khi);
        g_tkey[c] = (c == 0) ? 0u : klo;  // sentinel lower bound for chunk 0
    }
}

// ---------------- final quantization ----------------
__global__ void quant_kernel(const float4* __restrict__ x, float4* __restrict__ out, int n4) {
    __shared__ float s_mn[16], s_mx[16];
    __shared__ unsigned int s_t[16];
    if (threadIdx.x < 16) {
        s_mn[threadIdx.x] = g_mn[threadIdx.x];
        s_mx[threadIdx.x] = g_mx[threadIdx.x];
        s_t[threadIdx.x]  = g_tkey[threadIdx.x];
    }
    __syncthreads();
    int stride = gridDim.x * blockDim.x;
    for (int i = blockIdx.x * blockDim.x + threadIdx.x; i < n4; i += stride) {
        float4 v = x[i];
        float r[4] = {v.x, v.y, v.z, v.w};
#pragma unroll
        for (int k = 0; k < 4; ++k) {
            float xv = r[k];
            unsigned int key = f2key(xv);
            int c = (key >= s_t[8]) ? 8 : 0;
            if (key >= s_t[c + 4]) c += 4;
            if (key >= s_t[c + 2]) c += 2;
            if (key >= s_t[c + 1]) c += 1;
            float mn = s_mn[c], mx = s_mx[c];
            float outv;
            if (mn == mx) {
                outv = xv;
            } else {
                float st = (mx - mn) / 15.0f;
                if (st == 0.0f) st = 1.0f;
                float q = rintf((xv - mn) / st);
                outv = __fadd_rn(__fmul_rn(q, st), mn);  // match np: mul then add, no fma
            }
            r[k] = outv;
        }
        out[i] = make_float4(r[0], r[1], r[2], r[3]);
    }
}

// ---------------- launch ----------------
extern "C" void kernel_launch(void* const* d_in, const int* in_sizes, int n_in,
                              void* d_out, int out_size, void* d_ws, size_t ws_size,
                              hipStream_t stream) {
    const float* x = (const float*)d_in[0];
    float* out = (float*)d_out;
    int n  = in_sizes[0];
    int n4 = n / 4;

    zero_scratch<<<2048, 256, 0, stream>>>();
    hist1_kernel<<<H1_BLOCKS, 512, 0, stream>>>((const float4*)x, n4);
    reduce1_kernel<<<256, 256, 0, stream>>>();
    select1_kernel<<<1, 1024, 0, stream>>>((unsigned int)n);
    hist2_kernel<<<512, 512, 0, stream>>>((const float4*)x, n4);
    coarse2_kernel<<<8192, 256, 0, stream>>>();
    select2_kernel<<<1, 1024, 0, stream>>>();
    quant_kernel<<<4096, 256, 0, stream>>>((const float4*)x, (float4*)out, n4);
}

// Round 3
// 707.166 us; speedup vs baseline: 1.3028x; 1.3028x over previous
//
#include <hip/hip_runtime.h>
#include <math.h>

#define L1BITS 14
#define L1B 16384                  // 14-bit level-1 bins
#define L1W (L1B / 2)              // packed u16 words
#define H1_BLOCKS 512
#define SLOTS 32
#define L2BITS 9
#define L2B 512                    // 9-bit level-2 refine
#define L3BITS 9
#define L3B 512                    // 9-bit level-3 refine (14+9+9 = 32, exact)
#define H2_BLOCKS 256
#define H2W (SLOTS * L2B / 2)      // 8192 packed u16 words

// ---------------- device-global scratch ----------------
__device__ unsigned int g_part1[H1_BLOCKS * L1W];      // 16 MB, fully overwritten
__device__ unsigned int g_part2[H2_BLOCKS * H2W];      // 8 MB, fully overwritten
__device__ unsigned int g_hist1[L1B];                  // zeroed, atomic-accumulated
__device__ unsigned int g_coarse1[L1B / 256];          // 64 groups, zeroed
__device__ unsigned int g_hist2[SLOTS * L2B];          // zeroed, atomic-accumulated
__device__ unsigned int g_hist3[SLOTS * L3B];          // zeroed, sparse atomics
__device__ unsigned char g_sid1[L1B];                  // slot+1 per level-1 bin, zeroed
__device__ unsigned char g_sid2[SLOTS * L2B];          // slot+1 per (slot1,bin2), zeroed

__device__ unsigned int g_bin1[32], g_res1[32];
__device__ int          g_slot1[32];
__device__ unsigned int g_bin2[32], g_res2[32];
__device__ int          g_slot2[32];
__device__ float        g_mn[16], g_mx[16];
__device__ unsigned int g_tkey[16];

// monotone float->uint key
__device__ __forceinline__ unsigned int f2key(float f) {
    unsigned int b = __float_as_uint(f);
    return (b & 0x80000000u) ? ~b : (b | 0x80000000u);
}
__device__ __forceinline__ float key2f(unsigned int k) {
    unsigned int b = (k & 0x80000000u) ? (k & 0x7FFFFFFFu) : ~k;
    return __uint_as_float(b);
}

// ---------------- zero (all small now: ~230 KB total) ----------------
__global__ void zero_scratch() {
    int i = blockIdx.x * blockDim.x + threadIdx.x;
    int stride = gridDim.x * blockDim.x;
    for (int j = i; j < L1B; j += stride) g_hist1[j] = 0u;
    for (int j = i; j < SLOTS * L2B; j += stride) g_hist2[j] = 0u;
    for (int j = i; j < SLOTS * L3B; j += stride) g_hist3[j] = 0u;
    unsigned int* s1 = (unsigned int*)g_sid1;
    for (int j = i; j < L1B / 4; j += stride) s1[j] = 0u;
    unsigned int* s2 = (unsigned int*)g_sid2;
    for (int j = i; j < SLOTS * L2B / 4; j += stride) s2[j] = 0u;
    if (i < L1B / 256) g_coarse1[i] = 0u;
}

// ---------------- level 1: 14-bit histogram (LDS packed u16, 2 replicas) ------
__global__ void hist1_kernel(const float4* __restrict__ x, int n4) {
    __shared__ unsigned int h[2 * L1W];  // 64 KB: 2 sub-hists by wave parity
    for (int j = threadIdx.x; j < 2 * L1W; j += blockDim.x) h[j] = 0u;
    __syncthreads();
    unsigned int* hp = &h[((threadIdx.x >> 6) & 1) * L1W];
    int stride = gridDim.x * blockDim.x;
    for (int i = blockIdx.x * blockDim.x + threadIdx.x; i < n4; i += stride) {
        float4 v = x[i];
        float vv[4] = {v.x, v.y, v.z, v.w};
#pragma unroll
        for (int k = 0; k < 4; ++k) {
            unsigned int b = f2key(vv[k]) >> (32 - L1BITS);
            atomicAdd(&hp[b >> 1], 1u << ((b & 1) << 4));
        }
    }
    __syncthreads();
    // merge replicas; per-replica per-block halves < 32768, so no cross-carry
    for (int j = threadIdx.x; j < L1W; j += blockDim.x) {
        unsigned int a = h[j], b = h[L1W + j];
        unsigned int lo = (a & 0xFFFFu) + (b & 0xFFFFu);
        unsigned int hi = (a >> 16) + (b >> 16);
        g_part1[blockIdx.x * L1W + j] = lo | (hi << 16);
    }
}

// 64K threads, 8 chunks of 64 blocks; wave-reduced single atomic for coarse
__global__ void reduce1_kernel() {
    int t = blockIdx.x * blockDim.x + threadIdx.x;  // 65536 threads
    int w = t & (L1W - 1);
    int chunk = t >> 13;                            // 0..7
    const unsigned int* p = &g_part1[(chunk * 64) * L1W + w];
    unsigned int lo = 0, hi = 0;
#pragma unroll 8
    for (int b = 0; b < 64; ++b) {
        unsigned int u = p[b * L1W];
        lo += u & 0xFFFFu;
        hi += u >> 16;
    }
    atomicAdd(&g_hist1[2 * w], lo);
    atomicAdd(&g_hist1[2 * w + 1], hi);
    // w>>7 is uniform across the 64-lane wave -> reduce then one atomic
    unsigned int s = lo + hi;
#pragma unroll
    for (int off = 32; off; off >>= 1) s += (unsigned int)__shfl_down((int)s, off, 64);
    if ((threadIdx.x & 63) == 0) atomicAdd(&g_coarse1[w >> 7], s);
}

// ---------------- wave-parallel rank select ----------------
__device__ __forceinline__ void wave_select(const unsigned int* __restrict__ hist,
                                            int nbins, unsigned int r,
                                            unsigned int* out_bin, unsigned int* out_res) {
    int lane = threadIdx.x & 63;
    unsigned int base = 0;
    for (int k = 0; k < nbins; k += 64) {
        unsigned int v = hist[k + lane];
        unsigned int incl = v;
#pragma unroll
        for (int off = 1; off < 64; off <<= 1) {
            unsigned int t = (unsigned int)__shfl_up((int)incl, off, 64);
            if (lane >= off) incl += t;
        }
        unsigned int total = (unsigned int)__shfl((int)incl, 63, 64);
        if (r < base + total) {  // uniform branch
            unsigned long long m = __ballot(base + incl > r);
            int fl = __ffsll((long long)m) - 1;
            unsigned int incl_fl = (unsigned int)__shfl((int)incl, fl, 64);
            unsigned int v_fl = (unsigned int)__shfl((int)v, fl, 64);
            *out_bin = (unsigned int)(k + fl);
            *out_res = r - (base + incl_fl - v_fl);
            return;
        }
        base += total;
    }
    *out_bin = (unsigned int)(nbins - 1);
    *out_res = 0;  // unreachable
}

// ---------------- select level-1 + slot assignment (fused) ----------------
__global__ void select1_kernel(unsigned int n) {
    __shared__ unsigned int s_bin[32], s_res[32];
    int wid = threadIdx.x >> 6;  // 16 waves
    unsigned int M = n >> 4;
    for (int i = wid; i < 32; i += 16) {
        unsigned int c = (unsigned int)(i >> 1);
        unsigned int r = (i & 1) ? ((c + 1) * M - 1u) : (c * M);
        unsigned int g, rg, b, res;
        wave_select(g_coarse1, L1B / 256, r, &g, &rg);
        wave_select(g_hist1 + (g << 8), 256, rg, &b, &res);
        if ((threadIdx.x & 63) == 0) { s_bin[i] = (g << 8) | b; s_res[i] = res; }
    }
    __syncthreads();
    if (threadIdx.x == 0) {
        int nu = 0;
        for (int i = 0; i < 32; ++i) {
            unsigned int b = s_bin[i];
            if (g_sid1[b] == 0) g_sid1[b] = (unsigned char)(++nu);
            g_slot1[i] = g_sid1[b] - 1;
            g_bin1[i] = b;
            g_res1[i] = s_res[i];
        }
    }
}

// ---------------- level 2: 9-bit LDS refine of boundary bins ----------------
__global__ void hist2_kernel(const float4* __restrict__ x, int n4) {
    __shared__ unsigned int h2[H2W];      // 32 KB packed u16
    __shared__ unsigned char sid1[L1B];   // 16 KB
    for (int j = threadIdx.x; j < H2W; j += blockDim.x) h2[j] = 0u;
    unsigned int* s1w = (unsigned int*)sid1;
    for (int j = threadIdx.x; j < L1B / 4; j += blockDim.x) s1w[j] = ((const unsigned int*)g_sid1)[j];
    __syncthreads();
    int stride = gridDim.x * blockDim.x;
    for (int i = blockIdx.x * blockDim.x + threadIdx.x; i < n4; i += stride) {
        float4 v = x[i];
        float vv[4] = {v.x, v.y, v.z, v.w};
#pragma unroll
        for (int k = 0; k < 4; ++k) {
            unsigned int key = f2key(vv[k]);
            unsigned int s = sid1[key >> (32 - L1BITS)];
            if (s) {
                unsigned int c = ((s - 1) << L2BITS) | ((key >> L3BITS) & (L2B - 1));
                atomicAdd(&h2[c >> 1], 1u << ((c & 1) << 4));
            }
        }
    }
    __syncthreads();
    for (int j = threadIdx.x; j < H2W; j += blockDim.x)
        g_part2[blockIdx.x * H2W + j] = h2[j];
}

// 64K threads, 8 chunks of 32 blocks
__global__ void reduce2_kernel() {
    int t = blockIdx.x * blockDim.x + threadIdx.x;  // 65536 threads
    int w = t & (H2W - 1);
    int chunk = t >> 13;                            // 0..7
    const unsigned int* p = &g_part2[(chunk * 32) * H2W + w];
    unsigned int lo = 0, hi = 0;
#pragma unroll 8
    for (int b = 0; b < 32; ++b) {
        unsigned int u = p[b * H2W];
        lo += u & 0xFFFFu;
        hi += u >> 16;
    }
    atomicAdd(&g_hist2[2 * w], lo);
    atomicAdd(&g_hist2[2 * w + 1], hi);
}

// ---------------- select level-2 + slot2 assignment (fused) ----------------
__global__ void select2_kernel() {
    __shared__ unsigned int s_bin[32], s_res[32];
    int wid = threadIdx.x >> 6;  // 16 waves
    for (int i = wid; i < 32; i += 16) {
        int s = g_slot1[i];
        unsigned int b, res;
        wave_select(g_hist2 + (s << L2BITS), L2B, g_res1[i], &b, &res);
        if ((threadIdx.x & 63) == 0) { s_bin[i] = b; s_res[i] = res; }
    }
    __syncthreads();
    if (threadIdx.x == 0) {
        int nu = 0;
        for (int i = 0; i < 32; ++i) {
            int p = g_slot1[i] * L2B + (int)s_bin[i];
            if (g_sid2[p] == 0) g_sid2[p] = (unsigned char)(++nu);
            g_slot2[i] = g_sid2[p] - 1;
            g_bin2[i] = s_bin[i];
            g_res2[i] = s_res[i];
        }
    }
}

// ---------------- level 3: sparse (~20K participants) global atomics --------
__global__ void hist3_kernel(const float4* __restrict__ x, int n4) {
    __shared__ unsigned char sid1[L1B];          // 16 KB
    __shared__ unsigned char sid2[SLOTS * L2B];  // 16 KB
    unsigned int* s1w = (unsigned int*)sid1;
    for (int j = threadIdx.x; j < L1B / 4; j += blockDim.x) s1w[j] = ((const unsigned int*)g_sid1)[j];
    unsigned int* s2w = (unsigned int*)sid2;
    for (int j = threadIdx.x; j < SLOTS * L2B / 4; j += blockDim.x) s2w[j] = ((const unsigned int*)g_sid2)[j];
    __syncthreads();
    int stride = gridDim.x * blockDim.x;
    for (int i = blockIdx.x * blockDim.x + threadIdx.x; i < n4; i += stride) {
        float4 v = x[i];
        float vv[4] = {v.x, v.y, v.z, v.w};
#pragma unroll
        for (int k = 0; k < 4; ++k) {
            unsigned int key = f2key(vv[k]);
            unsigned int s = sid1[key >> (32 - L1BITS)];
            if (s) {
                unsigned int s2 = sid2[((s - 1) << L2BITS) | ((key >> L3BITS) & (L2B - 1))];
                if (s2) atomicAdd(&g_hist3[((s2 - 1) << L3BITS) | (key & (L3B - 1))], 1u);
            }
        }
    }
}

// ---------------- select level-3 + finalize (fused) ----------------
__global__ void select3_kernel() {
    __shared__ unsigned int s_key[32];
    int wid = threadIdx.x >> 6;  // 16 waves
    for (int i = wid; i < 32; i += 16) {
        int s2 = g_slot2[i];
        unsigned int b, res;
        wave_select(g_hist3 + (s2 << L3BITS), L3B, g_res2[i], &b, &res);
        if ((threadIdx.x & 63) == 0)
            s_key[i] = (g_bin1[i] << (32 - L1BITS)) | (g_bin2[i] << L3BITS) | b;  // exact key
    }
    __syncthreads();
    if (threadIdx.x < 16) {
        int c = threadIdx.x;
        unsigned int klo = s_key[2 * c];
        unsigned int khi = s_key[2 * c + 1];
        g_mn[c] = key2f(klo);
        g_mx[c] = key2f(khi);
        g_tkey[c] = (c == 0) ? 0u : klo;  // sentinel lower bound for chunk 0
    }
}

// ---------------- final quantization ----------------
__global__ void quant_kernel(const float4* __restrict__ x, float4* __restrict__ out, int n4) {
    __shared__ float s_mn[16], s_mx[16];
    __shared__ unsigned int s_t[16];
    if (threadIdx.x < 16) {
        s_mn[threadIdx.x] = g_mn[threadIdx.x];
        s_mx[threadIdx.x] = g_mx[threadIdx.x];
        s_t[threadIdx.x]  = g_tkey[threadIdx.x];
    }
    __syncthreads();
    int stride = gridDim.x * blockDim.x;
    for (int i = blockIdx.x * blockDim.x + threadIdx.x; i < n4; i += stride) {
        float4 v = x[i];
        float r[4] = {v.x, v.y, v.z, v.w};
#pragma unroll
        for (int k = 0; k < 4; ++k) {
            float xv = r[k];
            unsigned int key = f2key(xv);
            int c = (key >= s_t[8]) ? 8 : 0;
            if (key >= s_t[c + 4]) c += 4;
            if (key >= s_t[c + 2]) c += 2;
            if (key >= s_t[c + 1]) c += 1;
            float mn = s_mn[c], mx = s_mx[c];
            float outv;
            if (mn == mx) {
                outv = xv;
            } else {
                float st = (mx - mn) / 15.0f;
                if (st == 0.0f) st = 1.0f;
                float q = rintf((xv - mn) / st);
                outv = __fadd_rn(__fmul_rn(q, st), mn);  // match np: mul then add, no fma
            }
            r[k] = outv;
        }
        out[i] = make_float4(r[0], r[1], r[2], r[3]);
    }
}

// ---------------- launch ----------------
extern "C" void kernel_launch(void* const* d_in, const int* in_sizes, int n_in,
                              void* d_out, int out_size, void* d_ws, size_t ws_size,
                              hipStream_t stream) {
    const float* x = (const float*)d_in[0];
    float* out = (float*)d_out;
    int n  = in_sizes[0];
    int n4 = n / 4;

    zero_scratch<<<64, 256, 0, stream>>>();
    hist1_kernel<<<H1_BLOCKS, 512, 0, stream>>>((const float4*)x, n4);
    reduce1_kernel<<<256, 256, 0, stream>>>();
    select1_kernel<<<1, 1024, 0, stream>>>((unsigned int)n);
    hist2_kernel<<<H2_BLOCKS, 512, 0, stream>>>((const float4*)x, n4);
    reduce2_kernel<<<256, 256, 0, stream>>>();
    select2_kernel<<<1, 1024, 0, stream>>>();
    hist3_kernel<<<1024, 512, 0, stream>>>((const float4*)x, n4);
    select3_kernel<<<1, 1024, 0, stream>>>();
    quant_kernel<<<4096, 256, 0, stream>>>((const float4*)x, (float4*)out, n4);
}